// Round 1
// baseline (4024.020 us; speedup 1.0000x reference)
//
#include <hip/hip_runtime.h>
#include <math.h>

// Problem constants (B=4, S=8192, H=4096, E=64)
#define TOKENS 32768
#define KDIM   4096
#define NE     64
#define KSPLIT 8                 // waves per block = k-split ways
#define KPER   (KDIM / KSPLIT)   // 512 k per wave
#define KC     8                 // k per chunk (8 floats = 32B per expert row)
#define CHUNKS (KPER / KC)       // 64
#define TOKPB  128               // tokens per block: 64 lanes x 2 tokens/lane

#define AS1(p) ((const __attribute__((address_space(1))) void*)(p))
#define AS3(p) ((__attribute__((address_space(3))) void*)(p))

// Stage this wave's W chunk (64 experts x KC floats) into its private LDS buffer.
// global_load_lds: LDS dest = wave-uniform base + lane*16B.
// Issue j covers experts [j*32, j*32+32): lane l -> expert j*32 + l/2, row-byte (l&1)*16.
// LDS float offset written by lane l = j*256 + 4*l == e*KC + (l&1)*4  (e-major [e][k] layout).
#define STAGE(dst, c)                                                         \
    do {                                                                      \
        _Pragma("unroll")                                                     \
        for (int j = 0; j < 2; ++j) {                                         \
            const float* g = wsrc + (size_t)(j * 32 + (t >> 1)) * KDIM        \
                             + (c) * KC + (t & 1) * 4;                        \
            __builtin_amdgcn_global_load_lds(AS1(g), AS3((dst) + j * 256),    \
                                             16, 0, 0);                       \
        }                                                                     \
    } while (0)

#define LOADH(hreg, c)                                                        \
    do {                                                                      \
        hreg[0][0] = *reinterpret_cast<const float4*>(hrow0 + (c) * KC);      \
        hreg[0][1] = *reinterpret_cast<const float4*>(hrow0 + (c) * KC + 4);  \
        hreg[1][0] = *reinterpret_cast<const float4*>(hrow1 + (c) * KC);      \
        hreg[1][1] = *reinterpret_cast<const float4*>(hrow1 + (c) * KC + 4);  \
    } while (0)

// k ascending within chunk -> overall k sequential within the 512-slice,
// numerically identical to the previously-verified kernel.
#define FMA8(dst, hq0, hq1)                        \
    dst = fmaf((hq0).x, w0.x, dst);                \
    dst = fmaf((hq0).y, w0.y, dst);                \
    dst = fmaf((hq0).z, w0.z, dst);                \
    dst = fmaf((hq0).w, w0.w, dst);                \
    dst = fmaf((hq1).x, w1.x, dst);                \
    dst = fmaf((hq1).y, w1.y, dst);                \
    dst = fmaf((hq1).z, w1.z, dst);                \
    dst = fmaf((hq1).w, w1.w, dst);

#define COMPUTE(buf, hreg)                                                    \
    do {                                                                      \
        const float4* WL = reinterpret_cast<const float4*>(buf);              \
        _Pragma("unroll")                                                     \
        for (int e = 0; e < NE; ++e) {                                        \
            const float4 w0 = WL[2 * e];     /* uniform addr: broadcast */    \
            const float4 w1 = WL[2 * e + 1];                                  \
            FMA8(acc0[e], hreg[0][0], hreg[0][1])                             \
            FMA8(acc1[e], hreg[1][0], hreg[1][1])                             \
        }                                                                     \
    } while (0)

// 512 threads = 8 waves; wave kq owns k-slice [kq*512, kq*512+512).
// Each lane: 2 tokens (blockBase+t, blockBase+64+t), acc[2][64] in VGPRs.
// W streamed global->LDS via global_load_lds, per-wave double buffer, counted vmcnt
// (never drained to 0 in steady state). No __syncthreads in the main loop: each wave
// reads only its own staged region. __launch_bounds__(512,2): 2 waves/SIMD, VGPR<=256.
__global__ __launch_bounds__(512, 2)
void router_fwd(const float* __restrict__ Hs, const float* __restrict__ W,
                float* __restrict__ out_logits, float* __restrict__ out_aff,
                float* __restrict__ out_idx) {
    // 64 KiB LDS. Main loop: W staging [2 buf][KSPLIT][NE*KC] = 32 KiB (first half).
    // Epilogue (after barrier): reduction buffer [2][2][NE][64] = 64 KiB (aliased).
    __shared__ float smem[16384];

    const int t  = threadIdx.x & 63;   // lane
    const int kq = threadIdx.x >> 6;   // wave id = k-split index (wave-uniform)
    const int tok0 = blockIdx.x * TOKPB + t;   // token A; token B = tok0 + 64

    const float* __restrict__ hrow0 = Hs + (size_t)tok0 * KDIM + kq * KPER;
    const float* __restrict__ hrow1 = hrow0 + (size_t)64 * KDIM;
    const float* __restrict__ wsrc  = W + kq * KPER;

    float* wbuf0 = &smem[kq * (NE * KC)];
    float* wbuf1 = &smem[KSPLIT * (NE * KC) + kq * (NE * KC)];

    float acc0[NE], acc1[NE];
#pragma unroll
    for (int e = 0; e < NE; ++e) { acc0[e] = 0.0f; acc1[e] = 0.0f; }

    float4 hA[2][2], hB[2][2];

    // prologue: chunk 0 in flight (2 stage + 4 h = 6 outstanding)
    STAGE(wbuf0, 0);
    LOADH(hA, 0);

#pragma unroll 1
    for (int c = 0; c < CHUNKS; c += 2) {
        // even chunk c: compute from wbuf0/hA, prefetch c+1 -> wbuf1/hB
        asm volatile("s_waitcnt lgkmcnt(0)" ::: "memory"); // prior ds_reads of wbuf1 retired
        STAGE(wbuf1, c + 1);
        LOADH(hB, c + 1);
        asm volatile("s_waitcnt vmcnt(6)" ::: "memory");   // chunk c's 6 loads landed
        COMPUTE(wbuf0, hA);

        // odd chunk c+1: compute from wbuf1/hB, prefetch c+2 -> wbuf0/hA
        asm volatile("s_waitcnt lgkmcnt(0)" ::: "memory");
        if (c + 2 < CHUNKS) {
            STAGE(wbuf0, c + 2);
            LOADH(hA, c + 2);
            asm volatile("s_waitcnt vmcnt(6)" ::: "memory");
        } else {
            asm volatile("s_waitcnt vmcnt(0)" ::: "memory");
        }
        COMPUTE(wbuf1, hB);
    }

    // ---- tree reduction over 8 k-splits (same tree/order as verified kernel) ----
    __syncthreads(); // also drains all LDS traffic before aliasing smem
    float* red = smem;
#define RED(w, tt, e) red[((((w) * 2 + (tt)) * NE) + (e)) * 64 + t]

    if (kq == 4 || kq == 5) {
#pragma unroll
        for (int e = 0; e < NE; ++e) { RED(kq - 4, 0, e) = acc0[e]; RED(kq - 4, 1, e) = acc1[e]; }
    }
    __syncthreads();
    if (kq == 0 || kq == 1) {
#pragma unroll
        for (int e = 0; e < NE; ++e) { acc0[e] += RED(kq, 0, e); acc1[e] += RED(kq, 1, e); }
    }
    __syncthreads();
    if (kq == 6 || kq == 7) {
#pragma unroll
        for (int e = 0; e < NE; ++e) { RED(kq - 6, 0, e) = acc0[e]; RED(kq - 6, 1, e) = acc1[e]; }
    }
    __syncthreads();
    if (kq == 2 || kq == 3) {
#pragma unroll
        for (int e = 0; e < NE; ++e) { acc0[e] += RED(kq - 2, 0, e); acc1[e] += RED(kq - 2, 1, e); }
    }
    __syncthreads();
    if (kq == 2 || kq == 3) {
#pragma unroll
        for (int e = 0; e < NE; ++e) { RED(kq - 2, 0, e) = acc0[e]; RED(kq - 2, 1, e) = acc1[e]; }
    }
    __syncthreads();
    if (kq == 0 || kq == 1) {
#pragma unroll
        for (int e = 0; e < NE; ++e) { acc0[e] += RED(kq, 0, e); acc1[e] += RED(kq, 1, e); }
    }
    __syncthreads();
    // exchange halves so wave0 finalizes token A, wave1 finalizes token B (2x parallel tail)
    if (kq == 0) {
#pragma unroll
        for (int e = 0; e < NE; ++e) RED(0, 1, e) = acc1[e];
    } else if (kq == 1) {
#pragma unroll
        for (int e = 0; e < NE; ++e) RED(1, 0, e) = acc0[e];
    }
    __syncthreads();
    if (kq >= 2) return;

    float v[NE];
    if (kq == 0) {
#pragma unroll
        for (int e = 0; e < NE; ++e) v[e] = acc0[e] + RED(1, 0, e);
    } else {
#pragma unroll
        for (int e = 0; e < NE; ++e) v[e] = acc1[e] + RED(0, 1, e); // commutative: bit-identical
    }
    const int token = blockIdx.x * TOKPB + kq * 64 + t;

    // ---- store logits ----
    float* o0 = out_logits + (size_t)token * NE;
#pragma unroll
    for (int e = 0; e < NE; e += 4)
        *reinterpret_cast<float4*>(o0 + e) =
            make_float4(v[e], v[e + 1], v[e + 2], v[e + 3]);

    // ---- softmax (precise expf + precise div to track np) ----
    float m = v[0];
#pragma unroll
    for (int e = 1; e < NE; ++e) m = fmaxf(m, v[e]);
    float s = 0.0f;
#pragma unroll
    for (int e = 0; e < NE; ++e) { v[e] = expf(v[e] - m); s += v[e]; }
#pragma unroll
    for (int e = 0; e < NE; ++e) v[e] = v[e] / s;

    float* o1 = out_aff + (size_t)token * NE;
#pragma unroll
    for (int e = 0; e < NE; e += 4)
        *reinterpret_cast<float4*>(o1 + e) =
            make_float4(v[e], v[e + 1], v[e + 2], v[e + 3]);

    // ---- top-2 (stable: ties keep lower index, matching jax.lax.top_k) ----
    float b1 = -INFINITY, b2 = -INFINITY;
    int i1 = 0, i2 = 0;
#pragma unroll
    for (int e = 0; e < NE; ++e) {
        const float val = v[e];
        if (val > b1)      { b2 = b1; i2 = i1; b1 = val; i1 = e; }
        else if (val > b2) { b2 = val; i2 = e; }
    }
    *reinterpret_cast<float2*>(out_idx + (size_t)token * 2) =
        make_float2((float)i1, (float)i2);
}

extern "C" void kernel_launch(void* const* d_in, const int* in_sizes, int n_in,
                              void* d_out, int out_size, void* d_ws, size_t ws_size,
                              hipStream_t stream) {
    const float* hs = (const float*)d_in[0];  // [4,8192,4096] fp32
    const float* w  = (const float*)d_in[1];  // [64,4096] fp32
    float* out      = (float*)d_out;
    float* o_logits = out;                                  // 2097152 fp32
    float* o_aff    = out + (size_t)TOKENS * NE;            // 2097152 fp32
    float* o_idx    = out + 2 * (size_t)TOKENS * NE;        // 65536 (indices as fp32)

    dim3 grid(TOKENS / TOKPB); // 256 blocks = 1 per CU
    dim3 block(512);
    hipLaunchKernelGGL(router_fwd, grid, block, 0, stream, hs, w, o_logits, o_aff, o_idx);
}

// Round 2
// 1551.688 us; speedup vs baseline: 2.5933x; 2.5933x over previous
//
#include <hip/hip_runtime.h>
#include <math.h>

// Problem constants (B=4, S=8192, H=4096, E=64)
#define TOKENS 32768
#define KDIM   4096
#define NE     64
#define KSPLIT 8                 // waves per block = k-split ways
#define KPER   (KDIM / KSPLIT)   // 512 k per wave
#define KC     8                 // k per chunk
#define CHUNKS (KPER / KC)       // 64
#define TOKPB  128               // tokens per block: 64 lanes x 2 tokens/lane

// Load one KC-chunk of h for both tokens into scalar float arrays (vector loads).
#define LOADH(d0, d1, c)                                                      \
    do {                                                                      \
        _Pragma("unroll")                                                     \
        for (int q = 0; q < KC / 4; ++q) {                                    \
            const float4 v0 =                                                 \
                *reinterpret_cast<const float4*>(hrow0 + (c) * KC + 4 * q);   \
            d0[4 * q] = v0.x; d0[4 * q + 1] = v0.y;                           \
            d0[4 * q + 2] = v0.z; d0[4 * q + 3] = v0.w;                       \
            const float4 v1 =                                                 \
                *reinterpret_cast<const float4*>(hrow1 + (c) * KC + 4 * q);   \
            d1[4 * q] = v1.x; d1[4 * q + 1] = v1.y;                           \
            d1[4 * q + 2] = v1.z; d1[4 * q + 3] = v1.w;                       \
        }                                                                     \
    } while (0)

// W reads: wbase/kq/c/e are all wave-uniform (kq forced via readfirstlane), so
// wr[i] is a uniform load -> compiler emits s_load_dwordx4/x8 into SGPRs; the
// FMA uses the SGPR directly (v_fmac_f32 vdst, sgpr, vgpr). Scalar pipe only —
// no LDS, no per-lane VMEM for W. Full unroll keeps acc indices compile-time.
#define COMPUTE(c, h0, h1)                                                    \
    do {                                                                      \
        const float* __restrict__ wc = wbase + (c) * KC;                      \
        _Pragma("unroll")                                                     \
        for (int e = 0; e < NE; ++e) {                                        \
            const float* __restrict__ wr = wc + e * KDIM;                     \
            _Pragma("unroll")                                                 \
            for (int i = 0; i < KC; ++i) {                                    \
                const float wv = wr[i];                                       \
                acc0[e] = fmaf(h0[i], wv, acc0[e]);                           \
                acc1[e] = fmaf(h1[i], wv, acc1[e]);                           \
            }                                                                 \
        }                                                                     \
    } while (0)

// 512 threads = 8 waves; wave kq owns k-slice [kq*512, kq*512+512).
// Each lane: 2 tokens (blockBase+t, blockBase+64+t), acc[2][64] in VGPRs.
// __launch_bounds__(512,1): VGPR cap >= 256 under either interpretation of the
// 2nd arg (round-1's (512,2) produced a 128 cap -> full accumulator spill,
// 7.6 GB of scratch writes). Expected alloc ~200 -> 2 waves/SIMD, no spill.
__global__ __launch_bounds__(512, 1)
void router_fwd(const float* __restrict__ Hs, const float* __restrict__ W,
                float* __restrict__ out_logits, float* __restrict__ out_aff,
                float* __restrict__ out_idx) {
    __shared__ float red[2 * 2 * NE * 64]; // 64 KiB, epilogue reduction only

    const int t  = threadIdx.x & 63;                                  // lane
    const int kq = __builtin_amdgcn_readfirstlane(threadIdx.x >> 6);  // wave id, SGPR
    const int tok0 = blockIdx.x * TOKPB + t;  // token A; token B = tok0 + 64

    const float* __restrict__ hrow0 = Hs + (size_t)tok0 * KDIM + kq * KPER;
    const float* __restrict__ hrow1 = hrow0 + (size_t)64 * KDIM;
    const float* __restrict__ wbase = W + kq * KPER;  // uniform

    float acc0[NE], acc1[NE];
#pragma unroll
    for (int e = 0; e < NE; ++e) { acc0[e] = 0.0f; acc1[e] = 0.0f; }

    float hA0[KC], hA1[KC], hB0[KC], hB1[KC];

    LOADH(hA0, hA1, 0);
#pragma unroll 1
    for (int c = 0; c < CHUNKS; c += 2) {
        LOADH(hB0, hB1, c + 1);          // prefetch next chunk's h (4 loads in flight)
        COMPUTE(c, hA0, hA1);
        if (c + 2 < CHUNKS) LOADH(hA0, hA1, c + 2);
        COMPUTE(c + 1, hB0, hB1);
    }

    // ---- tree reduction over 8 k-splits (same tree as verified round-1 epilogue) ----
    __syncthreads();
#define RED(w, tt, e) red[((((w) * 2 + (tt)) * NE) + (e)) * 64 + t]

    if (kq == 4 || kq == 5) {
#pragma unroll
        for (int e = 0; e < NE; ++e) { RED(kq - 4, 0, e) = acc0[e]; RED(kq - 4, 1, e) = acc1[e]; }
    }
    __syncthreads();
    if (kq == 0 || kq == 1) {
#pragma unroll
        for (int e = 0; e < NE; ++e) { acc0[e] += RED(kq, 0, e); acc1[e] += RED(kq, 1, e); }
    }
    __syncthreads();
    if (kq == 6 || kq == 7) {
#pragma unroll
        for (int e = 0; e < NE; ++e) { RED(kq - 6, 0, e) = acc0[e]; RED(kq - 6, 1, e) = acc1[e]; }
    }
    __syncthreads();
    if (kq == 2 || kq == 3) {
#pragma unroll
        for (int e = 0; e < NE; ++e) { acc0[e] += RED(kq - 2, 0, e); acc1[e] += RED(kq - 2, 1, e); }
    }
    __syncthreads();
    if (kq == 2 || kq == 3) {
#pragma unroll
        for (int e = 0; e < NE; ++e) { RED(kq - 2, 0, e) = acc0[e]; RED(kq - 2, 1, e) = acc1[e]; }
    }
    __syncthreads();
    if (kq == 0 || kq == 1) {
#pragma unroll
        for (int e = 0; e < NE; ++e) { acc0[e] += RED(kq, 0, e); acc1[e] += RED(kq, 1, e); }
    }
    __syncthreads();
    // exchange halves so wave0 finalizes token A, wave1 finalizes token B
    if (kq == 0) {
#pragma unroll
        for (int e = 0; e < NE; ++e) RED(0, 1, e) = acc1[e];
    } else if (kq == 1) {
#pragma unroll
        for (int e = 0; e < NE; ++e) RED(1, 0, e) = acc0[e];
    }
    __syncthreads();
    if (kq >= 2) return;

    float v[NE];
    if (kq == 0) {
#pragma unroll
        for (int e = 0; e < NE; ++e) v[e] = acc0[e] + RED(1, 0, e);
    } else {
#pragma unroll
        for (int e = 0; e < NE; ++e) v[e] = acc1[e] + RED(0, 1, e);
    }
    const int token = blockIdx.x * TOKPB + kq * 64 + t;

    // ---- store logits ----
    float* o0 = out_logits + (size_t)token * NE;
#pragma unroll
    for (int e = 0; e < NE; e += 4)
        *reinterpret_cast<float4*>(o0 + e) =
            make_float4(v[e], v[e + 1], v[e + 2], v[e + 3]);

    // ---- softmax (precise expf + precise div to track np) ----
    float m = v[0];
#pragma unroll
    for (int e = 1; e < NE; ++e) m = fmaxf(m, v[e]);
    float s = 0.0f;
#pragma unroll
    for (int e = 0; e < NE; ++e) { v[e] = expf(v[e] - m); s += v[e]; }
#pragma unroll
    for (int e = 0; e < NE; ++e) v[e] = v[e] / s;

    float* o1 = out_aff + (size_t)token * NE;
#pragma unroll
    for (int e = 0; e < NE; e += 4)
        *reinterpret_cast<float4*>(o1 + e) =
            make_float4(v[e], v[e + 1], v[e + 2], v[e + 3]);

    // ---- top-2 (stable: ties keep lower index, matching jax.lax.top_k) ----
    float b1 = -INFINITY, b2 = -INFINITY;
    int i1 = 0, i2 = 0;
#pragma unroll
    for (int e = 0; e < NE; ++e) {
        const float val = v[e];
        if (val > b1)      { b2 = b1; i2 = i1; b1 = val; i1 = e; }
        else if (val > b2) { b2 = val; i2 = e; }
    }
    *reinterpret_cast<float2*>(out_idx + (size_t)token * 2) =
        make_float2((float)i1, (float)i2);
}

extern "C" void kernel_launch(void* const* d_in, const int* in_sizes, int n_in,
                              void* d_out, int out_size, void* d_ws, size_t ws_size,
                              hipStream_t stream) {
    const float* hs = (const float*)d_in[0];  // [4,8192,4096] fp32
    const float* w  = (const float*)d_in[1];  // [64,4096] fp32
    float* out      = (float*)d_out;
    float* o_logits = out;                                  // 2097152 fp32
    float* o_aff    = out + (size_t)TOKENS * NE;            // 2097152 fp32
    float* o_idx    = out + 2 * (size_t)TOKENS * NE;        // 65536 (indices as fp32)

    dim3 grid(TOKENS / TOKPB); // 256 blocks = 1 per CU
    dim3 block(512);
    hipLaunchKernelGGL(router_fwd, grid, block, 0, stream, hs, w, o_logits, o_aff, o_idx);
}